// Round 4
// baseline (167.560 us; speedup 1.0000x reference)
//
#include <hip/hip_runtime.h>
#include <hip/hip_bf16.h>

#define LN 96
#define BN 32
#define DM 128
#define EPN 95   // edges per receiver = L-1
#define HSTR 132 // padded f32 row stride for hsL (bank-derotated)

typedef __attribute__((ext_vector_type(8))) short s16x8;
typedef __attribute__((ext_vector_type(4))) float f32x4;

__device__ __forceinline__ float eluf(float x){ return x > 0.f ? x : __expf(x) - 1.f; }
__device__ __forceinline__ unsigned short f2bf(float f){
    unsigned u = __float_as_uint(f);
    return (unsigned short)((u + 0x7fff + ((u >> 16) & 1)) >> 16);
}
__device__ __forceinline__ float bf2f(unsigned short h){ return __uint_as_float(((unsigned)h) << 16); }

// ---------------- weight pack: 19 slots, fragment-order bf16 hi+lo ----------------
// slot layout (src row-major [k][n]): chunk c=(nt*4+ks)*64+lane holds 8 elems:
//   n = nt*16 + (lane&15), k = ks*32 + (lane>>4)*8 + e
// slots: 0..2 eW2[i]; 3 W0b; 4,5 eW1[0] S/R; 6 nW1[0]; 7 nW2[0]; 8,9 eW1[1] S/R;
//        10 nW1[1]; 11 nW2[1]; 12,13 eW1[2] S/R; 14 nW1[2]; 15 nW2[2]; 16,17 fW1 S/R;
//        18 fW2 (128x6, cols 6..15 zero-padded)
struct SrcTab { const float* p[19]; };

__global__ void conv_pack_kernel(SrcTab tab, unsigned short* __restrict__ hi,
                                 unsigned short* __restrict__ lo){
    int tid = blockIdx.x * 256 + threadIdx.x;   // 19*2048 = 38912
    int m = tid >> 11, c = tid & 2047;
    int l = c & 63, f = c >> 6;
    int n = (f >> 2) * 16 + (l & 15);
    int k0 = (f & 3) * 32 + (l >> 4) * 8;
    union { unsigned short us[8]; uint4 v; } ph, pl;
#pragma unroll
    for (int e = 0; e < 8; ++e){
        float x;
        if (m == 18) x = (n < 6) ? tab.p[18][(k0 + e) * 6 + n] : 0.f;
        else         x = tab.p[m][(k0 + e) * DM + n];
        unsigned short h = f2bf(x);
        ph.us[e] = h;
        pl.us[e] = f2bf(x - bf2f(h));
    }
    *(uint4*)(hi + (size_t)tid * 8) = ph.v;
    *(uint4*)(lo + (size_t)tid * 8) = pl.v;
}

// ---------------- node-stage helpers ----------------
__device__ __forceinline__ void nmm_core(const char* sT, int mt, int cs, int l,
        const unsigned short* __restrict__ wh, const unsigned short* __restrict__ wl,
        const float* __restrict__ bias, f32x4 acc[2]){
    const int l15 = l & 15, kgrp = l >> 4;
    const int arow = mt * 16 + l15;
    const char* rb = sT + arow * 256;
    const int swz = (arow & 7) << 4;
    s16x8 a[4];
#pragma unroll
    for (int ks = 0; ks < 4; ++ks)
        a[ks] = *(const s16x8*)(rb + (((ks * 32 + kgrp * 8) * 2) ^ swz));
#pragma unroll
    for (int ntl = 0; ntl < 2; ++ntl){
        float bb = bias ? bias[(cs * 2 + ntl) * 16 + l15] : 0.f;
        acc[ntl] = (f32x4){bb, bb, bb, bb};
        const unsigned short* bh = wh + (size_t)((cs * 2 + ntl) * 4) * 512;
        const unsigned short* bl = wl + (size_t)((cs * 2 + ntl) * 4) * 512;
#pragma unroll
        for (int ks = 0; ks < 4; ++ks)
            acc[ntl] = __builtin_amdgcn_mfma_f32_16x16x32_bf16(a[ks], *(const s16x8*)(bh + (ks * 64 + l) * 8), acc[ntl], 0, 0, 0);
#pragma unroll
        for (int ks = 0; ks < 4; ++ks)
            acc[ntl] = __builtin_amdgcn_mfma_f32_16x16x32_bf16(a[ks], *(const s16x8*)(bl + (ks * 64 + l) * 8), acc[ntl], 0, 0, 0);
    }
}

__device__ __forceinline__ void nstore_lds(char* dT, int mt, int cs, int l, f32x4 acc[2]){
    const int l15 = l & 15, kgrp = l >> 4;
#pragma unroll
    for (int ntl = 0; ntl < 2; ++ntl){
        int col = (cs * 2 + ntl) * 16 + l15;
#pragma unroll
        for (int i = 0; i < 4; ++i){
            int row = mt * 16 + kgrp * 4 + i;   // C/D: col=lane&15, row=(lane>>4)*4+i
            *(unsigned short*)(dT + ((row * 256 + col * 2) ^ ((row & 7) << 4))) = f2bf(eluf(acc[ntl][i]));
        }
    }
}

__device__ __forceinline__ void nstore_glb(float* __restrict__ dst, int row0, int mt, int cs, int l, f32x4 acc[2]){
    const int l15 = l & 15, kgrp = l >> 4;
#pragma unroll
    for (int ntl = 0; ntl < 2; ++ntl){
        int col = (cs * 2 + ntl) * 16 + l15;
#pragma unroll
        for (int i = 0; i < 4; ++i){
            int row = row0 + mt * 16 + kgrp * 4 + i;
            dst[(size_t)row * DM + col] = acc[ntl][i];
        }
    }
}

// ---------------- node stage: act = mlp(in); hs = act@WpS; hr = act@WpR + bp ----------------
// 48 blocks x 1024 thr; 64 rows/block; wave (mt = wv>>2, cs = wv&3) owns a 16x32 tile.
__global__ __launch_bounds__(1024) void node_mfma_kernel(
    const float* __restrict__ in,
    const float* __restrict__ W0a, const float* __restrict__ b0a,
    const unsigned short* __restrict__ w1h, const unsigned short* __restrict__ w1l, const float* __restrict__ b1,
    const unsigned short* __restrict__ w2h, const unsigned short* __restrict__ w2l, const float* __restrict__ b2,
    const unsigned short* __restrict__ wsh, const unsigned short* __restrict__ wsl,
    const unsigned short* __restrict__ wrh, const unsigned short* __restrict__ wrl, const float* __restrict__ bp,
    float* __restrict__ hs, float* __restrict__ hr, int mode){
    __shared__ char tA[64 * 256];
    __shared__ char tB[64 * 256];
    const int t = threadIdx.x;
    const int row0 = blockIdx.x * 64;
    const int wv = t >> 6, l = t & 63;

    // stage -> tA (mode0: fused scalar K=4 layer W0a)
    {
        int rr = t >> 4, q = t & 15, c0 = q * 8;
        int swz = (rr & 7) << 4;
        union { unsigned short us[8]; uint4 v; } pk;
        if (mode == 0){
            int row = row0 + rr, b = row / LN, ll = row - b * LN;
            float4 x = *(const float4*)(in + (size_t)(ll * BN + b) * 4);
#pragma unroll
            for (int j = 0; j < 8; ++j){
                int cc = c0 + j;
                float a = b0a[cc] + x.x * W0a[cc] + x.y * W0a[DM + cc]
                        + x.z * W0a[2 * DM + cc] + x.w * W0a[3 * DM + cc];
                pk.us[j] = f2bf(eluf(a));
            }
        } else {
            const float* src = in + (size_t)(row0 + rr) * DM + c0;
            float4 f0 = *(const float4*)src;
            float4 f1 = *(const float4*)(src + 4);
            pk.us[0] = f2bf(f0.x); pk.us[1] = f2bf(f0.y); pk.us[2] = f2bf(f0.z); pk.us[3] = f2bf(f0.w);
            pk.us[4] = f2bf(f1.x); pk.us[5] = f2bf(f1.y); pk.us[6] = f2bf(f1.z); pk.us[7] = f2bf(f1.w);
        }
        *(uint4*)(tA + ((rr * 256 + c0 * 2) ^ swz)) = pk.v;
    }
    __syncthreads();
    const int mt = wv >> 2, cs = wv & 3;
    f32x4 acc[2];
    const char* src;
    if (mode == 1){
        nmm_core(tA, mt, cs, l, w1h, w1l, b1, acc);
        nstore_lds(tB, mt, cs, l, acc);
        __syncthreads();
        nmm_core(tB, mt, cs, l, w2h, w2l, b2, acc);
        nstore_lds(tA, mt, cs, l, acc);   // safe: this phase reads only tB
        __syncthreads();
        src = tA;
    } else {
        nmm_core(tA, mt, cs, l, w2h, w2l, b2, acc);
        nstore_lds(tB, mt, cs, l, acc);
        __syncthreads();
        src = tB;
    }
    nmm_core(src, mt, cs, l, wsh, wsl, nullptr, acc);
    nstore_glb(hs, row0, mt, cs, l, acc);
    nmm_core(src, mt, cs, l, wrh, wrl, bp, acc);
    nstore_glb(hr, row0, mt, cs, l, acc);
}

// ---------------- edge kernel: block = (b, rgroup of 12 receivers), hs staged ONCE in LDS ----
__global__ __launch_bounds__(1024) void edge_kernel(
    const float* __restrict__ hs, const float* __restrict__ hr,
    const unsigned short* __restrict__ w2pk, const float* __restrict__ b2,
    float* __restrict__ g){
    __shared__ float hsL[LN * HSTR];
    __shared__ float hrL[12 * DM];
    __shared__ char tA[LN * 256];
    __shared__ char tB[LN * 256];
    __shared__ float redbuf[2][2][DM];
    const int blk = blockIdx.x;
    const int b = blk >> 3, rg = blk & 7;
    const int t = threadIdx.x, wv = t >> 6, l = t & 63;
    const int l15 = l & 15, kgrp = l >> 4;

    // stage hs[b] (96x128) and this group's 12 hr rows
#pragma unroll
    for (int rep = 0; rep < 3; ++rep){
        int task = t + rep * 1024;
        int rr = task >> 5, c4 = (task & 31) * 4;
        *(float4*)(hsL + rr * HSTR + c4) = *(const float4*)(hs + ((size_t)(b * LN) + rr) * DM + c4);
    }
    if (t < 384){
        int rr = t >> 5, c4 = (t & 31) * 4;
        *(float4*)(hrL + rr * DM + c4) = *(const float4*)(hr + ((size_t)(b * LN + rg * 12 + rr)) * DM + c4);
    }
    // B-frags held in registers for all 12 receivers
    const int csW = wv & 3;
    s16x8 bfr[2][4];
#pragma unroll
    for (int ntl = 0; ntl < 2; ++ntl)
#pragma unroll
        for (int ks = 0; ks < 4; ++ks)
            bfr[ntl][ks] = *(const s16x8*)(w2pk + (size_t)(((csW * 2 + ntl) * 4 + ks) * 64 + l) * 8);
    float b20 = b2[(csW * 2) * 16 + l15], b21 = b2[(csW * 2 + 1) * 16 + l15];
    __syncthreads();

    const int tm = wv >> 3, half = (wv >> 2) & 1;
    for (int it = 0; it < 6; ++it){
        const int r0 = rg * 12 + it * 2, r1 = r0 + 1;
        // build 2 y1 tiles from LDS
#pragma unroll
        for (int rep = 0; rep < 3; ++rep){
            int task = t + rep * 1024;
            int tt = task >= 1536;
            int rem = task - tt * 1536;
            int rr = rem >> 4, c0 = (rem & 15) * 8;
            char* tile = tt ? tB : tA;
            int r = tt ? r1 : r0;
            int rloc = r - rg * 12;
            int swz = (rr & 7) << 4;
            union { unsigned short us[8]; uint4 v; } pk;
            if (rr < EPN){
                int j = rr + (rr >= r);
                const float* hp = hsL + j * HSTR + c0;
                const float* rp = hrL + rloc * DM + c0;
                f32x4 h0 = *(const f32x4*)hp, h1 = *(const f32x4*)(hp + 4);
                f32x4 v0 = *(const f32x4*)rp, v1 = *(const f32x4*)(rp + 4);
#pragma unroll
                for (int e = 0; e < 4; ++e){
                    pk.us[e]     = f2bf(eluf(h0[e] + v0[e]));
                    pk.us[e + 4] = f2bf(eluf(h1[e] + v1[e]));
                }
            } else pk.v = make_uint4(0, 0, 0, 0);
            *(uint4*)(tile + ((rr * 256 + c0 * 2) ^ swz)) = pk.v;
        }
        __syncthreads();
        // MFMA: 8-wave team per tile; wave = (tm, half, csW)
        const char* tile = tm ? tB : tA;
        f32x4 acc[3][2] = {};
#pragma unroll
        for (int m3 = 0; m3 < 3; ++m3){
            int arow = half * 48 + m3 * 16 + l15;
            const char* rb = tile + arow * 256;
            int swz = (arow & 7) << 4;
#pragma unroll
            for (int ks = 0; ks < 4; ++ks){
                s16x8 a = *(const s16x8*)(rb + (((ks * 32 + kgrp * 8) * 2) ^ swz));
                acc[m3][0] = __builtin_amdgcn_mfma_f32_16x16x32_bf16(a, bfr[0][ks], acc[m3][0], 0, 0, 0);
                acc[m3][1] = __builtin_amdgcn_mfma_f32_16x16x32_bf16(a, bfr[1][ks], acc[m3][1], 0, 0, 0);
            }
        }
        // epilogue: +b2, elu, column-sum over this half's rows
        float c0s = 0.f, c1s = 0.f;
#pragma unroll
        for (int m3 = 0; m3 < 3; ++m3)
#pragma unroll
            for (int i = 0; i < 4; ++i){
                int row = half * 48 + m3 * 16 + kgrp * 4 + i;
                if (row < EPN){
                    c0s += eluf(acc[m3][0][i] + b20);
                    c1s += eluf(acc[m3][1][i] + b21);
                }
            }
        c0s += __shfl_xor(c0s, 16); c0s += __shfl_xor(c0s, 32);
        c1s += __shfl_xor(c1s, 16); c1s += __shfl_xor(c1s, 32);
        if (l < 16){
            redbuf[tm][half][(csW * 2) * 16 + l]     = c0s;
            redbuf[tm][half][(csW * 2 + 1) * 16 + l] = c1s;
        }
        __syncthreads();
        if (t < 256){
            int ttm = t >> 7, c = t & 127;
            int r = ttm ? r1 : r0;
            g[((size_t)(b * LN) + r) * DM + c] = (redbuf[ttm][0][c] + redbuf[ttm][1][c]) * (1.f / 95.f);
        }
        // no extra sync: tile reads finished before redbuf sync; g-write rejoins at next barrier
    }
}

// ---------------- final kernel: edge-clone with N=16 (6 valid cols), hi+lo fW2 ----------------
__global__ __launch_bounds__(1024) void final_kernel(
    const float* __restrict__ hs, const float* __restrict__ hr,
    const unsigned short* __restrict__ wfh, const unsigned short* __restrict__ wfl,
    const float* __restrict__ fb2, float* __restrict__ out){
    __shared__ float hsL[LN * HSTR];
    __shared__ float hrL[12 * DM];
    __shared__ char tiles[4][LN * 256];
    const int blk = blockIdx.x;
    const int b = blk >> 3, rg = blk & 7;
    const int t = threadIdx.x, wv = t >> 6, l = t & 63;
    const int l15 = l & 15, kgrp = l >> 4;
#pragma unroll
    for (int rep = 0; rep < 3; ++rep){
        int task = t + rep * 1024;
        int rr = task >> 5, c4 = (task & 31) * 4;
        *(float4*)(hsL + rr * HSTR + c4) = *(const float4*)(hs + ((size_t)(b * LN) + rr) * DM + c4);
    }
    if (t < 384){
        int rr = t >> 5, c4 = (t & 31) * 4;
        *(float4*)(hrL + rr * DM + c4) = *(const float4*)(hr + ((size_t)(b * LN + rg * 12 + rr)) * DM + c4);
    }
    s16x8 fh[4], flo[4];
#pragma unroll
    for (int ks = 0; ks < 4; ++ks){
        fh[ks]  = *(const s16x8*)(wfh + (size_t)(ks * 64 + l) * 8);
        flo[ks] = *(const s16x8*)(wfl + (size_t)(ks * 64 + l) * 8);
    }
    float fb2v = (l15 < 6) ? fb2[l15] : 0.f;
    __syncthreads();
    const int tm = wv >> 2, ws = wv & 3;
    for (int it = 0; it < 3; ++it){
        // build 4 tiles (receivers rg*12 + it*4 + 0..3)
#pragma unroll
        for (int rep = 0; rep < 6; ++rep){
            int task = t + rep * 1024;
            int tt = task / 1536;
            int rem = task - tt * 1536;
            int rr = rem >> 4, c0 = (rem & 15) * 8;
            int r = rg * 12 + it * 4 + tt;
            int rloc = r - rg * 12;
            int swz = (rr & 7) << 4;
            union { unsigned short us[8]; uint4 v; } pk;
            if (rr < EPN){
                int j = rr + (rr >= r);
                const float* hp = hsL + j * HSTR + c0;
                const float* rp = hrL + rloc * DM + c0;
                f32x4 h0 = *(const f32x4*)hp, h1 = *(const f32x4*)(hp + 4);
                f32x4 v0 = *(const f32x4*)rp, v1 = *(const f32x4*)(rp + 4);
#pragma unroll
                for (int e = 0; e < 4; ++e){
                    pk.us[e]     = f2bf(eluf(h0[e] + v0[e]));
                    pk.us[e + 4] = f2bf(eluf(h1[e] + v1[e]));
                }
            } else pk.v = make_uint4(0, 0, 0, 0);
            *(uint4*)(tiles[tt] + ((rr * 256 + c0 * 2) ^ swz)) = pk.v;
        }
        __syncthreads();
        int r = rg * 12 + it * 4 + tm;
        const char* tile = tiles[tm];
        float* obase = out + ((size_t)b * (LN * EPN) + (size_t)r * EPN) * 6;
#pragma unroll
        for (int mtp = 0; mtp < 2; ++mtp){
            int mt = ws + mtp * 4;
            if (mt > 5) break;
            int arow = mt * 16 + l15;
            const char* rb = tile + arow * 256;
            int swz = (arow & 7) << 4;
            s16x8 a[4];
#pragma unroll
            for (int ks = 0; ks < 4; ++ks)
                a[ks] = *(const s16x8*)(rb + (((ks * 32 + kgrp * 8) * 2) ^ swz));
            f32x4 acc = (f32x4){0.f, 0.f, 0.f, 0.f};
#pragma unroll
            for (int ks = 0; ks < 4; ++ks)
                acc = __builtin_amdgcn_mfma_f32_16x16x32_bf16(a[ks], fh[ks], acc, 0, 0, 0);
#pragma unroll
            for (int ks = 0; ks < 4; ++ks)
                acc = __builtin_amdgcn_mfma_f32_16x16x32_bf16(a[ks], flo[ks], acc, 0, 0, 0);
            if (l15 < 6){
#pragma unroll
                for (int i = 0; i < 4; ++i){
                    int row = mt * 16 + kgrp * 4 + i;
                    if (row < EPN) obase[(size_t)row * 6 + l15] = acc[i] + fb2v;
                }
            }
        }
        __syncthreads();
    }
}

extern "C" void kernel_launch(void* const* d_in, const int* in_sizes, int n_in,
                              void* d_out, int out_size, void* d_ws, size_t ws_size,
                              hipStream_t stream) {
    const float* inputs = (const float*)d_in[0];
    const float* W0a = (const float*)d_in[3];
    const float* b0a = (const float*)d_in[4];
    const float* W0b = (const float*)d_in[5];
    const float* b0b = (const float*)d_in[6];
    const float* eW1 = (const float*)d_in[7];
    const float* eb1 = (const float*)d_in[8];
    const float* eW2 = (const float*)d_in[9];
    const float* eb2 = (const float*)d_in[10];
    const float* nW1 = (const float*)d_in[11];
    const float* nb1 = (const float*)d_in[12];
    const float* nW2 = (const float*)d_in[13];
    const float* nb2 = (const float*)d_in[14];
    const float* fW1 = (const float*)d_in[15];
    const float* fb1 = (const float*)d_in[16];
    const float* fW2 = (const float*)d_in[17];
    const float* fb2 = (const float*)d_in[18];
    float* out = (float*)d_out;

    const int NR = BN * LN;            // 3072 node rows
    float* hs = (float*)d_ws;
    float* hr = hs + NR * DM;
    float* g  = hr + NR * DM;
    unsigned short* whi = (unsigned short*)(g + NR * DM);  // 19 x 16384 packed hi
    unsigned short* wlo = whi + 19 * 16384;                // 19 x 16384 packed lo

    SrcTab tab;
    tab.p[0] = eW2;          tab.p[1] = eW2 + 16384;  tab.p[2] = eW2 + 32768;
    tab.p[3] = W0b;
    tab.p[4] = eW1;          tab.p[5] = eW1 + 16384;
    tab.p[6] = nW1;          tab.p[7] = nW2;          tab.p[8] = eW1 + 32768;  tab.p[9]  = eW1 + 49152;
    tab.p[10] = nW1 + 16384; tab.p[11] = nW2 + 16384; tab.p[12] = eW1 + 65536; tab.p[13] = eW1 + 81920;
    tab.p[14] = nW1 + 32768; tab.p[15] = nW2 + 32768; tab.p[16] = fW1;         tab.p[17] = fW1 + 16384;
    tab.p[18] = fW2;

    #define WM(m) (whi + (m) * 16384), (wlo + (m) * 16384)

    conv_pack_kernel<<<152, 256, 0, stream>>>(tab, whi, wlo);
    // block 0: fused scalar layer0 (W0a) + W0b + proj eW1[0]
    node_mfma_kernel<<<48, 1024, 0, stream>>>(inputs, W0a, b0a, WM(3), b0b,
                                              WM(3), b0b, WM(4), WM(5), eb1, hs, hr, 0);
    edge_kernel<<<256, 1024, 0, stream>>>(hs, hr, whi + 0 * 16384, eb2, g);
    // block 1
    node_mfma_kernel<<<48, 1024, 0, stream>>>(g, W0a, b0a, WM(6), nb1, WM(7), nb2,
                                              WM(8), WM(9), eb1 + 128, hs, hr, 1);
    edge_kernel<<<256, 1024, 0, stream>>>(hs, hr, whi + 1 * 16384, eb2 + 128, g);
    // block 2
    node_mfma_kernel<<<48, 1024, 0, stream>>>(g, W0a, b0a, WM(10), nb1 + 128, WM(11), nb2 + 128,
                                              WM(12), WM(13), eb1 + 256, hs, hr, 1);
    edge_kernel<<<256, 1024, 0, stream>>>(hs, hr, whi + 2 * 16384, eb2 + 256, g);
    // block 3 + final
    node_mfma_kernel<<<48, 1024, 0, stream>>>(g, W0a, b0a, WM(14), nb1 + 256, WM(15), nb2 + 256,
                                              WM(16), WM(17), fb1, hs, hr, 1);
    final_kernel<<<256, 1024, 0, stream>>>(hs, hr, WM(18), fb2, out);
    #undef WM
}